// Round 11
// baseline (2303.792 us; speedup 1.0000x reference)
//
#include <hip/hip_runtime.h>
#include <hip/hip_fp16.h>

#define NSTATES 256
#define SEQ 1024
#define NSYM 100

// ---------- prep: W[a][i][j] f32 -> WB[a][w][j][i'] fp16 (13 MB, once) ----------
// WB[(((a*16 + w)*256) + j)*16 + i'] = W[a][16w + i'][j]
// i.e. per (symbol, wave) a contiguous 256x16 fp16 panel: output block's W^T.
__global__ __launch_bounds__(256) void prep_b(const float* __restrict__ W,
                                              __half* __restrict__ WB) {
    __shared__ float tile[16][256];
    int a = blockIdx.y;
    int w = blockIdx.x;
    int t = threadIdx.x;
    const float* src = W + ((size_t)a * 256 + w * 16) * 256;
#pragma unroll
    for (int r = 0; r < 16; r++) tile[r][t] = src[r * 256 + t];
    __syncthreads();
    __half tmp[16];
#pragma unroll
    for (int i = 0; i < 16; i++) tmp[i] = __float2half(tile[i][t]);
    ushort4* dst = (ushort4*)(WB + ((((size_t)a * 16 + w) * 256) + t) * 16);
    const ushort4* s = (const ushort4*)tmp;
#pragma unroll
    for (int q = 0; q < 4; q++) dst[q] = s[q];
}

// Raw workgroup barrier that drains ONLY DS ops (h writes / shuffles).
// Inline-asm s_barrier is opaque to the backend -> no vmcnt(0) drain, so the
// global prefetch loads stay in flight across the barrier.
#define BARRIER_LDS_ONLY() asm volatile("s_waitcnt lgkmcnt(0)\n\ts_barrier" ::: "memory")

// ---------- main chain kernel: output-partitioned, lgkm-only barrier, pinned prefetch ----------
// grid = B, block = 1024 (16 waves). Wave w owns outputs i in [16w,16w+16).
// Lane l accumulates i' = (l&3)*4..+3 over j = k*16 + (l>>2), k=0..15; a 4-level
// shfl_xor butterfly (masks 4,8,16,32) completes the dot products in-register.
// Lanes 0..3 write float4 to the ping-pong h buffer; one lgkm-only barrier per step.
// W loads for step t+1 are issued at phase start and PINNED there by
// sched_barrier(0) so the scheduler cannot sink them into the compute.
__global__ __launch_bounds__(1024) void pann_fwd_b(const int* __restrict__ xs,
                                                   const int* __restrict__ lengths,
                                                   const __half* __restrict__ WB,
                                                   const float* __restrict__ lin_w,
                                                   const float* __restrict__ lin_b,
                                                   float* __restrict__ out) {
    __shared__ float h[2][NSTATES];
    __shared__ float opart[2][NSTATES];
    __shared__ int xrow[SEQ];

    int b = blockIdx.x;
    int tid = threadIdx.x;
    int w = tid >> 6;
    int lane = tid & 63;

    xrow[tid] = xs[(size_t)b * SEQ + tid];
    if (tid < NSTATES) h[0][tid] = (tid == 0) ? 1.0f : 0.0f;
    int len = lengths[b];
    __syncthreads();

    // ushort4 view: per symbol 16384 ushort4; per wave panel 1024 ushort4.
    const ushort4* Wb4 = (const ushort4*)WB;
    const ushort4* wl = Wb4 + w * 1024 + lane;
    int hidx = lane >> 2;           // j offset within each k-group

    ushort4 Ra[16], Rb[16];
    {
        int x0 = __builtin_amdgcn_readfirstlane(xrow[0]);
        const ushort4* p = wl + (size_t)x0 * 16384;
#pragma unroll
        for (int k = 0; k < 16; k++) Ra[k] = p[k * 64];
    }

    int cur = 0;
    int t = 0;
#define PHASE(RC, RN)                                                         \
    {                                                                         \
        int tn = t + 1; if (tn >= len) tn = t;                                \
        int xn = __builtin_amdgcn_readfirstlane(xrow[tn]);                    \
        const ushort4* pn = wl + (size_t)xn * 16384;                          \
        _Pragma("unroll")                                                     \
        for (int k = 0; k < 16; k++) RN[k] = pn[k * 64];                      \
        __builtin_amdgcn_sched_barrier(0);                                    \
        float a0 = 0.f, a1 = 0.f, a2 = 0.f, a3 = 0.f;                         \
        _Pragma("unroll")                                                     \
        for (int k = 0; k < 16; k++) {                                        \
            float hj = h[cur][k * 16 + hidx];                                 \
            float2 f0 = __half22float2(*(const __half2*)&RC[k].x);            \
            float2 f1 = __half22float2(*(const __half2*)&RC[k].z);            \
            a0 = fmaf(f0.x, hj, a0);                                          \
            a1 = fmaf(f0.y, hj, a1);                                          \
            a2 = fmaf(f1.x, hj, a2);                                          \
            a3 = fmaf(f1.y, hj, a3);                                          \
        }                                                                     \
        _Pragma("unroll")                                                     \
        for (int m = 4; m <= 32; m <<= 1) {                                   \
            a0 += __shfl_xor(a0, m, 64);                                      \
            a1 += __shfl_xor(a1, m, 64);                                      \
            a2 += __shfl_xor(a2, m, 64);                                      \
            a3 += __shfl_xor(a3, m, 64);                                      \
        }                                                                     \
        if (lane < 4)                                                         \
            *(float4*)&h[cur ^ 1][w * 16 + lane * 4] =                        \
                make_float4(a0, a1, a2, a3);                                  \
        BARRIER_LDS_ONLY();                                                   \
        cur ^= 1;                                                             \
        t++;                                                                  \
    }

    while (t < len) {
        PHASE(Ra, Rb);
        if (t >= len) break;
        PHASE(Rb, Ra);
    }
#undef PHASE

    // ---- head: out[b,k] = lin_w[k,:] @ h + lin_b[k] ----
    if (tid < NSTATES) {
        float hv = h[cur][tid];
        opart[0][tid] = hv * lin_w[tid];
        opart[1][tid] = hv * lin_w[NSTATES + tid];
    }
    __syncthreads();
    for (int s = 128; s > 0; s >>= 1) {
        if (tid < s) {
            opart[0][tid] += opart[0][tid + s];
            opart[1][tid] += opart[1][tid + s];
        }
        __syncthreads();
    }
    if (tid == 0) {
        out[b * 2 + 0] = opart[0][0] + lin_b[0];
        out[b * 2 + 1] = opart[1][0] + lin_b[1];
    }
}

// ---------- fallback: f32 no-transpose path (only if d_ws too small) ----------
__global__ __launch_bounds__(1024) void pann_fwd_nt(const int* __restrict__ xs,
                                                    const int* __restrict__ lengths,
                                                    const float* __restrict__ W,
                                                    const float* __restrict__ lin_w,
                                                    const float* __restrict__ lin_b,
                                                    float* __restrict__ out) {
    __shared__ float hbuf[2][NSTATES];
    __shared__ float opart[2][NSTATES];
    __shared__ int xrow[SEQ];

    int b = blockIdx.x;
    int tid = threadIdx.x;
    int w = tid >> 6;
    int lane = tid & 63;

    xrow[tid] = xs[(size_t)b * SEQ + tid];
    if (tid < NSTATES) hbuf[0][tid] = (tid == 0) ? 1.0f : 0.0f;
    int len = lengths[b];
    __syncthreads();

    int cur = 0;
    for (int t = 0; t < len; t++) {
        int x = xrow[t];
        const float4* wp = (const float4*)(W + (size_t)x * (NSTATES * NSTATES));
        float4 hv = *(const float4*)&hbuf[cur][lane << 2];
#pragma unroll
        for (int ii = 0; ii < 4; ii++) {
            int i = (w << 4) + ii * 4;
#pragma unroll
            for (int k = 0; k < 4; k++) {
                int row = i + k;
                float4 wv = wp[row * 64 + lane];
                float p = wv.x * hv.x + wv.y * hv.y + wv.z * hv.z + wv.w * hv.w;
#pragma unroll
                for (int off = 32; off > 0; off >>= 1) p += __shfl_down(p, off);
                if (lane == 0) hbuf[cur ^ 1][row] = p;
            }
        }
        __syncthreads();
        cur ^= 1;
    }

    if (tid < NSTATES) {
        float hv = hbuf[cur][tid];
        opart[0][tid] = hv * lin_w[tid];
        opart[1][tid] = hv * lin_w[NSTATES + tid];
    }
    __syncthreads();
    for (int s = 128; s > 0; s >>= 1) {
        if (tid < s) {
            opart[0][tid] += opart[0][tid + s];
            opart[1][tid] += opart[1][tid + s];
        }
        __syncthreads();
    }
    if (tid == 0) {
        out[b * 2 + 0] = opart[0][0] + lin_b[0];
        out[b * 2 + 1] = opart[1][0] + lin_b[1];
    }
}

extern "C" void kernel_launch(void* const* d_in, const int* in_sizes, int n_in,
                              void* d_out, int out_size, void* d_ws, size_t ws_size,
                              hipStream_t stream) {
    const int* xs = (const int*)d_in[0];
    const int* lengths = (const int*)d_in[1];
    const float* W = (const float*)d_in[2];
    const float* lin_w = (const float*)d_in[3];
    const float* lin_b = (const float*)d_in[4];
    float* out = (float*)d_out;

    int B = in_sizes[0] / SEQ;
    size_t wbytes = (size_t)NSYM * NSTATES * NSTATES * sizeof(__half);

    if (ws_size >= wbytes) {
        __half* WB = (__half*)d_ws;
        dim3 tg(16, NSYM);
        prep_b<<<tg, 256, 0, stream>>>(W, WB);
        pann_fwd_b<<<B, 1024, 0, stream>>>(xs, lengths, WB, lin_w, lin_b, out);
    } else {
        pann_fwd_nt<<<B, 1024, 0, stream>>>(xs, lengths, W, lin_w, lin_b, out);
    }
}

// Round 12
// 2255.582 us; speedup vs baseline: 1.0214x; 1.0214x over previous
//
#include <hip/hip_runtime.h>
#include <hip/hip_fp16.h>

#define NSTATES 256
#define SEQ 1024
#define NSYM 100

typedef unsigned long long u64;

// ---------- prep: W[a][i][j] f32 -> WB[a][w][j][i'] fp16 (13 MB, once) ----------
// WB[(((a*16 + w)*256) + j)*16 + i'] = W[a][16w + i'][j]
__global__ __launch_bounds__(256) void prep_b(const float* __restrict__ W,
                                              __half* __restrict__ WB) {
    __shared__ float tile[16][256];
    int a = blockIdx.y;
    int w = blockIdx.x;
    int t = threadIdx.x;
    const float* src = W + ((size_t)a * 256 + w * 16) * 256;
#pragma unroll
    for (int r = 0; r < 16; r++) tile[r][t] = src[r * 256 + t];
    __syncthreads();
    __half tmp[16];
#pragma unroll
    for (int i = 0; i < 16; i++) tmp[i] = __float2half(tile[i][t]);
    ushort4* dst = (ushort4*)(WB + ((((size_t)a * 16 + w) * 256) + t) * 16);
    const ushort4* s = (const ushort4*)tmp;
#pragma unroll
    for (int q = 0; q < 4; q++) dst[q] = s[q];
}

// lgkm-only workgroup barrier: DS ops drained, global loads stay in flight.
#define BARRIER_LDS_ONLY() asm volatile("s_waitcnt lgkmcnt(0)\n\ts_barrier" ::: "memory")

// One 8B W-fragment load, forced at this program point, result in a named VGPR pair.
#define LD_OFF(dst, base, OFF) \
    asm volatile("global_load_dwordx2 %0, %1, off offset:" #OFF : "=v"(dst) : "v"(base))

// 16 fragments = this lane's 128B slice of the wave's 8KB panel for one symbol.
// Imm offset is 13-bit signed, so split k=0..7 (base) and k=8..15 (base+4096).
#define LOAD16(R, B0, B1)    \
    LD_OFF(R[0], B0, 0);     \
    LD_OFF(R[1], B0, 512);   \
    LD_OFF(R[2], B0, 1024);  \
    LD_OFF(R[3], B0, 1536);  \
    LD_OFF(R[4], B0, 2048);  \
    LD_OFF(R[5], B0, 2560);  \
    LD_OFF(R[6], B0, 3072);  \
    LD_OFF(R[7], B0, 3584);  \
    LD_OFF(R[8], B1, 0);     \
    LD_OFF(R[9], B1, 512);   \
    LD_OFF(R[10], B1, 1024); \
    LD_OFF(R[11], B1, 1536); \
    LD_OFF(R[12], B1, 2048); \
    LD_OFF(R[13], B1, 2560); \
    LD_OFF(R[14], B1, 3072); \
    LD_OFF(R[15], B1, 3584)

// ---------- main chain kernel: asm double-buffer, counted vmcnt, lgkm-only barrier ----------
// grid = B, block = 1024 (16 waves). Wave w owns outputs i in [16w,16w+16).
// Lane l: outputs i' = (l&3)*4..+3, inner j = k*16 + (l>>2); 4-level shfl_xor
// butterfly completes the dot products. Loads for step t+1 are inline-asm
// global_load_dwordx2 (cannot be sunk/split), wait is a counted vmcnt(16):
// this phase's 16 loads remain in flight across the lgkm-only barrier.
__global__ __launch_bounds__(1024) void pann_fwd_a(const int* __restrict__ xs,
                                                   const int* __restrict__ lengths,
                                                   const __half* __restrict__ WB,
                                                   const float* __restrict__ lin_w,
                                                   const float* __restrict__ lin_b,
                                                   float* __restrict__ out) {
    __shared__ float h[2][NSTATES];
    __shared__ float opart[2][NSTATES];
    __shared__ int xrow[SEQ];

    int b = blockIdx.x;
    int tid = threadIdx.x;
    int w = tid >> 6;
    int lane = tid & 63;

    xrow[tid] = xs[(size_t)b * SEQ + tid];
    if (tid < NSTATES) h[0][tid] = (tid == 0) ? 1.0f : 0.0f;
    int len = lengths[b];
    __syncthreads();   // also drains prologue vmem: vmcnt clean slate

    int hidx = lane >> 2;
    // Byte address of this lane's first fragment within the symbol-0 panel.
    u64 lane_base = (u64)(const char*)WB + ((u64)w * 1024 + (u64)lane) * 8;

    u64 Ra[16], Rb[16];
    {
        int x0 = __builtin_amdgcn_readfirstlane(xrow[0]);
        u64 b0 = lane_base + (u64)x0 * 131072u;
        u64 b1 = b0 + 4096u;
        LOAD16(Ra, b0, b1);
    }

    int cur = 0;
    int t = 0;
#define PHASE(RC, RN)                                                         \
    {                                                                         \
        int tn = t + 1; if (tn >= len) tn = t;                                \
        int xn = __builtin_amdgcn_readfirstlane(xrow[tn]);                    \
        u64 nb0 = lane_base + (u64)xn * 131072u;                              \
        u64 nb1 = nb0 + 4096u;                                                \
        LOAD16(RN, nb0, nb1);                                                 \
        asm volatile("s_waitcnt vmcnt(16)");                                  \
        __builtin_amdgcn_sched_barrier(0);                                    \
        float a0 = 0.f, a1 = 0.f, a2 = 0.f, a3 = 0.f;                         \
        _Pragma("unroll")                                                     \
        for (int k = 0; k < 16; k++) {                                        \
            float hj = h[cur][k * 16 + hidx];                                 \
            unsigned lo = (unsigned)RC[k];                                    \
            unsigned hi = (unsigned)(RC[k] >> 32);                            \
            __half2 p0 = __builtin_bit_cast(__half2, lo);                     \
            __half2 p1 = __builtin_bit_cast(__half2, hi);                     \
            float2 f0 = __half22float2(p0);                                   \
            float2 f1 = __half22float2(p1);                                   \
            a0 = fmaf(f0.x, hj, a0);                                          \
            a1 = fmaf(f0.y, hj, a1);                                          \
            a2 = fmaf(f1.x, hj, a2);                                          \
            a3 = fmaf(f1.y, hj, a3);                                          \
        }                                                                     \
        _Pragma("unroll")                                                     \
        for (int m = 4; m <= 32; m <<= 1) {                                   \
            a0 += __shfl_xor(a0, m, 64);                                      \
            a1 += __shfl_xor(a1, m, 64);                                      \
            a2 += __shfl_xor(a2, m, 64);                                      \
            a3 += __shfl_xor(a3, m, 64);                                      \
        }                                                                     \
        if (lane < 4)                                                         \
            *(float4*)&h[cur ^ 1][w * 16 + lane * 4] =                        \
                make_float4(a0, a1, a2, a3);                                  \
        BARRIER_LDS_ONLY();                                                   \
        cur ^= 1;                                                             \
        t++;                                                                  \
    }

    while (t < len) {
        PHASE(Ra, Rb);
        if (t >= len) break;
        PHASE(Rb, Ra);
    }
#undef PHASE

    // ---- head: out[b,k] = lin_w[k,:] @ h + lin_b[k] ----
    __syncthreads();   // drains the trailing prefetch loads too
    if (tid < NSTATES) {
        float hv = h[cur][tid];
        opart[0][tid] = hv * lin_w[tid];
        opart[1][tid] = hv * lin_w[NSTATES + tid];
    }
    __syncthreads();
    for (int s = 128; s > 0; s >>= 1) {
        if (tid < s) {
            opart[0][tid] += opart[0][tid + s];
            opart[1][tid] += opart[1][tid + s];
        }
        __syncthreads();
    }
    if (tid == 0) {
        out[b * 2 + 0] = opart[0][0] + lin_b[0];
        out[b * 2 + 1] = opart[1][0] + lin_b[1];
    }
}

// ---------- fallback: f32 no-transpose path (only if d_ws too small) ----------
__global__ __launch_bounds__(1024) void pann_fwd_nt(const int* __restrict__ xs,
                                                    const int* __restrict__ lengths,
                                                    const float* __restrict__ W,
                                                    const float* __restrict__ lin_w,
                                                    const float* __restrict__ lin_b,
                                                    float* __restrict__ out) {
    __shared__ float hbuf[2][NSTATES];
    __shared__ float opart[2][NSTATES];
    __shared__ int xrow[SEQ];

    int b = blockIdx.x;
    int tid = threadIdx.x;
    int w = tid >> 6;
    int lane = tid & 63;

    xrow[tid] = xs[(size_t)b * SEQ + tid];
    if (tid < NSTATES) hbuf[0][tid] = (tid == 0) ? 1.0f : 0.0f;
    int len = lengths[b];
    __syncthreads();

    int cur = 0;
    for (int t = 0; t < len; t++) {
        int x = xrow[t];
        const float4* wp = (const float4*)(W + (size_t)x * (NSTATES * NSTATES));
        float4 hv = *(const float4*)&hbuf[cur][lane << 2];
#pragma unroll
        for (int ii = 0; ii < 4; ii++) {
            int i = (w << 4) + ii * 4;
#pragma unroll
            for (int k = 0; k < 4; k++) {
                int row = i + k;
                float4 wv = wp[row * 64 + lane];
                float p = wv.x * hv.x + wv.y * hv.y + wv.z * hv.z + wv.w * hv.w;
#pragma unroll
                for (int off = 32; off > 0; off >>= 1) p += __shfl_down(p, off);
                if (lane == 0) hbuf[cur ^ 1][row] = p;
            }
        }
        __syncthreads();
        cur ^= 1;
    }

    if (tid < NSTATES) {
        float hv = hbuf[cur][tid];
        opart[0][tid] = hv * lin_w[tid];
        opart[1][tid] = hv * lin_w[NSTATES + tid];
    }
    __syncthreads();
    for (int s = 128; s > 0; s >>= 1) {
        if (tid < s) {
            opart[0][tid] += opart[0][tid + s];
            opart[1][tid] += opart[1][tid + s];
        }
        __syncthreads();
    }
    if (tid == 0) {
        out[b * 2 + 0] = opart[0][0] + lin_b[0];
        out[b * 2 + 1] = opart[1][0] + lin_b[1];
    }
}

extern "C" void kernel_launch(void* const* d_in, const int* in_sizes, int n_in,
                              void* d_out, int out_size, void* d_ws, size_t ws_size,
                              hipStream_t stream) {
    const int* xs = (const int*)d_in[0];
    const int* lengths = (const int*)d_in[1];
    const float* W = (const float*)d_in[2];
    const float* lin_w = (const float*)d_in[3];
    const float* lin_b = (const float*)d_in[4];
    float* out = (float*)d_out;

    int B = in_sizes[0] / SEQ;
    size_t wbytes = (size_t)NSYM * NSTATES * NSTATES * sizeof(__half);

    if (ws_size >= wbytes) {
        __half* WB = (__half*)d_ws;
        dim3 tg(16, NSYM);
        prep_b<<<tg, 256, 0, stream>>>(W, WB);
        pann_fwd_a<<<B, 1024, 0, stream>>>(xs, lengths, WB, lin_w, lin_b, out);
    } else {
        pann_fwd_nt<<<B, 1024, 0, stream>>>(xs, lengths, W, lin_w, lin_b, out);
    }
}

// Round 13
// 1904.328 us; speedup vs baseline: 1.2098x; 1.1844x over previous
//
#include <hip/hip_runtime.h>
#include <hip/hip_fp16.h>

#define NST 256
#define SEQ 1024
#define NSYM 100

typedef unsigned long long u64;

// Address-space types for the global_load_lds builtin (AS1 global, AS3 LDS).
typedef __attribute__((address_space(1))) const void gas_t;
typedef __attribute__((address_space(3))) void las_t;

// One 16B-per-lane direct global->LDS copy. LDS dest is the WAVE-UNIFORM base;
// hardware writes base + lane*16. No register def => the compiler's waitcnt
// pass has nothing to guard; ordering is ours via counted vmcnt.
#define GLOAD16(gsrc, ldst) \
    __builtin_amdgcn_global_load_lds((gas_t*)(gsrc), (las_t*)(ldst), 16, 0, 0)

// Stage one 8KB half-panel for this wave: 8 instructions of 1KB.
#define STAGE8(GB, SB)                                                  \
    _Pragma("unroll")                                                   \
    for (int m_ = 0; m_ < 8; ++m_)                                      \
        GLOAD16((const char*)(GB) + m_ * 1024 + l * 16,                 \
                (char*)(SB) + m_ * 1024)

#define SBAR0() __builtin_amdgcn_sched_barrier(0)
// Counted wait: allow 8 loads (the just-issued next-half group) to remain
// in flight; guarantees the older 8 (this half's data) have landed in LDS.
#define WAITV8() do { SBAR0(); asm volatile("s_waitcnt vmcnt(8)"); SBAR0(); } while (0)
// Raw barrier: drain DS only (h handoff); global staging loads stay in flight.
#define STEPBAR() do { SBAR0(); asm volatile("s_waitcnt lgkmcnt(0)"); \
                       __builtin_amdgcn_s_barrier(); SBAR0(); } while (0)

// ---------- prep: W[a][i][j] f32 -> WC[a][w][j][i'] fp16 panels ----------
// WC[(((a*8 + w)*256) + j)*32 + i'] = W[a][32w + i'][j]  (per (a,w): 16KB linear)
__global__ __launch_bounds__(256) void prep_c(const float* __restrict__ W,
                                              __half* __restrict__ WC) {
    __shared__ float tile[32][256];
    int a = blockIdx.y;
    int w = blockIdx.x;
    int t = threadIdx.x;
    const float* src = W + ((size_t)a * 256 + w * 32) * 256;
#pragma unroll
    for (int r = 0; r < 32; ++r) tile[r][t] = src[(size_t)r * 256 + t];
    __syncthreads();
    __half tmp[32];
#pragma unroll
    for (int i = 0; i < 32; ++i) tmp[i] = __float2half(tile[i][t]);
    ushort4* d4 = (ushort4*)(WC + ((((size_t)a * 8 + w) * 256) + t) * 32);
    const ushort4* s4 = (const ushort4*)tmp;
#pragma unroll
    for (int q = 0; q < 8; ++q) d4[q] = s4[q];
}

// ---------- main chain kernel: LDS-pipelined, counted vmcnt, raw barrier ----------
// grid = B, block = 512 (8 waves), one chain per block.
// Wave w owns output rows [32w, 32w+32). Lane l: r=l&7 -> rows 4r..4r+3,
// jo=l>>3 -> j = k*8+jo, k=0..31. Butterfly over masks 8,16,32 completes dots.
// Per step: vmcnt(8); compute lo(k<16); stage(t+1,lo); vmcnt(8); compute hi;
// stage(t+1,hi); butterfly; h write; lgkm-only barrier. 16 VMEM/step exactly.
__global__ __launch_bounds__(512) void pann_fwd_p(const int* __restrict__ xs,
                                                  const int* __restrict__ lengths,
                                                  const __half* __restrict__ WC,
                                                  const float* __restrict__ lin_w,
                                                  const float* __restrict__ lin_b,
                                                  float* __restrict__ out) {
    __shared__ float h[2][NST];
    __shared__ float opart[2][NST];
    __shared__ int xrow[SEQ];
    __shared__ __align__(16) u64 sLo[8][1024];   // 64KB: lo half (k=0..15), 8KB/wave
    __shared__ __align__(16) u64 sHi[8][1024];   // 64KB: hi half (k=16..31)

    int b = blockIdx.x;
    int tid = threadIdx.x;
    int w = tid >> 6;
    int l = tid & 63;
    int jo = l >> 3;

    xrow[tid] = xs[(size_t)b * SEQ + tid];
    xrow[tid + 512] = xs[(size_t)b * SEQ + tid + 512];
    if (tid < NST) h[0][tid] = (tid == 0) ? 1.0f : 0.0f;
    int len = lengths[b];

    const char* gW = (const char*)WC;
    u64* sLoW = sLo[w];
    u64* sHiW = sHi[w];

    // Prologue: stage step 0 (symbol read from global; xrow not yet visible).
    int x0 = xs[(size_t)b * SEQ];
    {
        const char* g0 = gW + ((size_t)x0 * 8 + (size_t)w) * 16384;
        STAGE8(g0, sLoW);
        STAGE8(g0 + 8192, sHiW);
    }
    __syncthreads();   // h/xrow visibility; drains prologue staging (once)

    int cur = 0;
    for (int t = 0; t < len; ++t) {
        int tn = (t + 1 < len) ? t + 1 : t;
        int xn = __builtin_amdgcn_readfirstlane(xrow[tn]);
        const char* gn = gW + ((size_t)xn * 8 + (size_t)w) * 16384;

        float a0 = 0.f, a1 = 0.f, a2 = 0.f, a3 = 0.f;

        WAITV8();   // lo half of step t resident
#pragma unroll
        for (int kk = 0; kk < 16; ++kk) {
            float hj = h[cur][kk * 8 + jo];
            u64 v = sLoW[kk * 64 + l];
            unsigned lo32 = (unsigned)v, hi32 = (unsigned)(v >> 32);
            float2 f0 = __half22float2(__builtin_bit_cast(__half2, lo32));
            float2 f1 = __half22float2(__builtin_bit_cast(__half2, hi32));
            a0 = fmaf(f0.x, hj, a0);
            a1 = fmaf(f0.y, hj, a1);
            a2 = fmaf(f1.x, hj, a2);
            a3 = fmaf(f1.y, hj, a3);
        }
        SBAR0();
        STAGE8(gn, sLoW);          // refill lo with step t+1

        WAITV8();   // hi half of step t resident
#pragma unroll
        for (int kk = 0; kk < 16; ++kk) {
            float hj = h[cur][128 + kk * 8 + jo];
            u64 v = sHiW[kk * 64 + l];
            unsigned lo32 = (unsigned)v, hi32 = (unsigned)(v >> 32);
            float2 f0 = __half22float2(__builtin_bit_cast(__half2, lo32));
            float2 f1 = __half22float2(__builtin_bit_cast(__half2, hi32));
            a0 = fmaf(f0.x, hj, a0);
            a1 = fmaf(f0.y, hj, a1);
            a2 = fmaf(f1.x, hj, a2);
            a3 = fmaf(f1.y, hj, a3);
        }
        SBAR0();
        STAGE8(gn + 8192, sHiW);   // refill hi with step t+1

#pragma unroll
        for (int m = 8; m <= 32; m <<= 1) {
            a0 += __shfl_xor(a0, m, 64);
            a1 += __shfl_xor(a1, m, 64);
            a2 += __shfl_xor(a2, m, 64);
            a3 += __shfl_xor(a3, m, 64);
        }
        if (l < 8)
            *(float4*)&h[cur ^ 1][w * 32 + l * 4] = make_float4(a0, a1, a2, a3);
        STEPBAR();
        cur ^= 1;
    }

    __syncthreads();   // drain trailing staging; h final stable

    // ---- head: out[b,k] = lin_w[k,:] @ h + lin_b[k] ----
    if (tid < NST) {
        float hv = h[cur][tid];
        opart[0][tid] = hv * lin_w[tid];
        opart[1][tid] = hv * lin_w[NST + tid];
    }
    __syncthreads();
    for (int s = 128; s > 0; s >>= 1) {
        if (tid < s) {
            opart[0][tid] += opart[0][tid + s];
            opart[1][tid] += opart[1][tid + s];
        }
        __syncthreads();
    }
    if (tid == 0) {
        out[b * 2 + 0] = opart[0][0] + lin_b[0];
        out[b * 2 + 1] = opart[1][0] + lin_b[1];
    }
}

// ---------- fallback: f32 no-transpose path (only if d_ws too small) ----------
__global__ __launch_bounds__(1024) void pann_fwd_nt(const int* __restrict__ xs,
                                                    const int* __restrict__ lengths,
                                                    const float* __restrict__ W,
                                                    const float* __restrict__ lin_w,
                                                    const float* __restrict__ lin_b,
                                                    float* __restrict__ out) {
    __shared__ float hbuf[2][NST];
    __shared__ float opart[2][NST];
    __shared__ int xrow[SEQ];

    int b = blockIdx.x;
    int tid = threadIdx.x;
    int w = tid >> 6;
    int lane = tid & 63;

    xrow[tid] = xs[(size_t)b * SEQ + tid];
    if (tid < NST) hbuf[0][tid] = (tid == 0) ? 1.0f : 0.0f;
    int len = lengths[b];
    __syncthreads();

    int cur = 0;
    for (int t = 0; t < len; t++) {
        int x = xrow[t];
        const float4* wp = (const float4*)(W + (size_t)x * (NST * NST));
        float4 hv = *(const float4*)&hbuf[cur][lane << 2];
#pragma unroll
        for (int ii = 0; ii < 4; ii++) {
            int i = (w << 4) + ii * 4;
#pragma unroll
            for (int k = 0; k < 4; k++) {
                int row = i + k;
                float4 wv = wp[row * 64 + lane];
                float p = wv.x * hv.x + wv.y * hv.y + wv.z * hv.z + wv.w * hv.w;
#pragma unroll
                for (int off = 32; off > 0; off >>= 1) p += __shfl_down(p, off);
                if (lane == 0) hbuf[cur ^ 1][row] = p;
            }
        }
        __syncthreads();
        cur ^= 1;
    }

    if (tid < NST) {
        float hv = hbuf[cur][tid];
        opart[0][tid] = hv * lin_w[tid];
        opart[1][tid] = hv * lin_w[NST + tid];
    }
    __syncthreads();
    for (int s = 128; s > 0; s >>= 1) {
        if (tid < s) {
            opart[0][tid] += opart[0][tid + s];
            opart[1][tid] += opart[1][tid + s];
        }
        __syncthreads();
    }
    if (tid == 0) {
        out[b * 2 + 0] = opart[0][0] + lin_b[0];
        out[b * 2 + 1] = opart[1][0] + lin_b[1];
    }
}

extern "C" void kernel_launch(void* const* d_in, const int* in_sizes, int n_in,
                              void* d_out, int out_size, void* d_ws, size_t ws_size,
                              hipStream_t stream) {
    const int* xs = (const int*)d_in[0];
    const int* lengths = (const int*)d_in[1];
    const float* W = (const float*)d_in[2];
    const float* lin_w = (const float*)d_in[3];
    const float* lin_b = (const float*)d_in[4];
    float* out = (float*)d_out;

    int B = in_sizes[0] / SEQ;
    size_t wbytes = (size_t)NSYM * NST * NST * sizeof(__half);

    if (ws_size >= wbytes) {
        __half* WC = (__half*)d_ws;
        dim3 tg(8, NSYM);
        prep_c<<<tg, 256, 0, stream>>>(W, WC);
        pann_fwd_p<<<B, 512, 0, stream>>>(xs, lengths, WC, lin_w, lin_b, out);
    } else {
        pann_fwd_nt<<<B, 1024, 0, stream>>>(xs, lengths, W, lin_w, lin_b, out);
    }
}